// Round 14
// baseline (65.499 us; speedup 1.0000x reference)
//
#include <hip/hip_runtime.h>
#include <math.h>

#define NTOK 4096
#define IND 768
#define DD 256
#define DD2 512
#define DHH 128
#define NEXP 51
#define TM 32
#define NTILE_MAX 179
#define NWCONV 968

typedef __attribute__((ext_vector_type(4))) float f32x4;
typedef __attribute__((ext_vector_type(8))) short short8;

__device__ __forceinline__ float gelu_f(float x) {
    return 0.5f * x * (1.0f + erff(x * 0.70710678118654752440f));
}
__device__ __forceinline__ ushort f2bf(float x) {
    unsigned u = __float_as_uint(x);
    return (ushort)((u + 0x7fffu + ((u >> 16) & 1u)) >> 16);
}
// async global->LDS, 16B/lane; LDS dest = wave-uniform base + lane*16
__device__ __forceinline__ void gl_lds16(const ushort* g, ushort* l) {
    __builtin_amdgcn_global_load_lds(
        (const __attribute__((address_space(1))) unsigned int*)g,
        (__attribute__((address_space(3))) unsigned int*)l, 16, 0, 0);
}

// ---- fused pre-pass (round-13 proven; TM=32 tile build) ----
__global__ __launch_bounds__(256) void k_pre(
    const float* __restrict__ pw1, const float* __restrict__ pw2,
    const float* __restrict__ fw, const float* __restrict__ dw1,
    const float* __restrict__ aW,
    ushort* __restrict__ pw1T, ushort* __restrict__ pw2T, ushort* __restrict__ fwT,
    ushort* __restrict__ dw1T, ushort* __restrict__ aWT,
    const float* __restrict__ tokens,
    const float* __restrict__ ln_g, const float* __restrict__ ln_b,
    const float* __restrict__ sw1, const float* __restrict__ sb1,
    const float* __restrict__ sw2, const float* __restrict__ sb2,
    const float* __restrict__ ew1, const float* __restrict__ eb1,
    const float* __restrict__ ew2, const float* __restrict__ eb2,
    ushort* __restrict__ x_ln, ushort* __restrict__ enh,
    const int* __restrict__ levels,
    const float* __restrict__ spw1, const float* __restrict__ spb1,
    const float* __restrict__ spw2, const float* __restrict__ spb2,
    const float* __restrict__ lw1, const float* __restrict__ lb1,
    const float* __restrict__ lw2, const float* __restrict__ lb2,
    const int* __restrict__ ph, const int* __restrict__ pw,
    const float* __restrict__ fb,
    int* __restrict__ sorted, int* __restrict__ tpos, int* __restrict__ tcnt,
    int* __restrict__ texp, int* __restrict__ meta, float* __restrict__ ctail) {
    __shared__ float T[64][65];
    __shared__ int cnt[NEXP], cur[NEXP], offS[NEXP + 1], tileoff[NEXP + 1];
    __shared__ int expS[NTOK];
    __shared__ float hsS[64], hlS[64], cf[128];
    int t = threadIdx.x;

    if (blockIdx.x == 0) {
        if (t < NEXP) cnt[t] = 0;
        if (t < 64) {
            float p0 = (float)ph[0], p1 = (float)pw[0];
            float lvl = (float)levels[0];
            hsS[t] = fmaxf(0.f, p0 * spw1[t] + p1 * spw1[64 + t] + spb1[t]);
            hlS[t] = fmaxf(0.f, lvl * lw1[t] + lb1[t]);
        }
        __syncthreads();
        int myidx[16];
        #pragma unroll
        for (int i = 0; i < 16; ++i) {
            int n = t + i * 256;
            int id = min(max(levels[n * 2], 0), NEXP - 1);
            myidx[i] = id;
            atomicAdd(&cnt[id], 1);
        }
        if (t < 64) {
            float v = spb2[t];
            for (int j = 0; j < 64; ++j) v += hsS[j] * spw2[j * 64 + t];
            cf[t] = v;
        } else if (t < 128) {
            int k = t - 64;
            float v = lb2[k];
            for (int j = 0; j < 64; ++j) v += hlS[j] * lw2[j * 64 + k];
            cf[64 + k] = v;
        }
        __syncthreads();
        if (t == 0) {
            int a = 0, ta = 0;
            for (int e = 0; e < NEXP; ++e) {
                offS[e] = a; cur[e] = a; tileoff[e] = ta;
                ta += (cnt[e] + TM - 1) / TM;
                a += cnt[e];
            }
            offS[NEXP] = a; tileoff[NEXP] = ta;
            meta[0] = ta;
        }
        __syncthreads();
        #pragma unroll
        for (int i = 0; i < 16; ++i) {
            int n = t + i * 256;
            int p = atomicAdd(&cur[myidx[i]], 1);
            sorted[p] = n;
            expS[p] = myidx[i];
        }
        {
            float v = fb[t];
            for (int j = 0; j < 128; ++j) v += cf[j] * fw[(size_t)(128 + j) * DD + t];
            ctail[t] = v;
        }
        __syncthreads();
        #pragma unroll
        for (int i = 0; i < 16; ++i) {
            int p = t + i * 256;
            int e = expS[p];
            int rel = p - offS[e];
            if ((rel & (TM - 1)) == 0) {
                int ti = tileoff[e] + (rel / TM);
                tpos[ti] = p;
                tcnt[ti] = min(TM, offS[e + 1] - p);
                texp[ti] = e;
            }
        }
        return;
    }
    if (blockIdx.x < 1 + NWCONV) {
        int b = blockIdx.x - 1;
        const float* src; ushort* dst; int R, C;
        if (b < 96)       { src = pw1; dst = pw1T; R = IND; C = DD2; }
        else if (b < 128) { b -= 96;  src = pw2; dst = pw2T; R = DD2; C = DD; }
        else if (b < 144) { b -= 128; src = fw;  dst = fwT;  R = DD;  C = DD; }
        else if (b < 152) { b -= 144; src = dw1; dst = dw1T; R = DD;  C = DHH; }
        else { b -= 152; int e = b >> 4; b &= 15;
               src = aW + (size_t)e * DD * DD; dst = aWT + (size_t)e * DD * DD;
               R = DD; C = DD; }
        int tpc = C >> 6;
        int tr = b / tpc, tc = b - tr * tpc;
        int lr = t >> 6, lc = t & 63;
        #pragma unroll
        for (int i = 0; i < 16; ++i) {
            int r = i * 4 + lr;
            T[r][lc] = src[(size_t)(tr * 64 + r) * C + tc * 64 + lc];
        }
        __syncthreads();
        #pragma unroll
        for (int i = 0; i < 16; ++i) {
            int r = i * 4 + lr;
            dst[(size_t)(tc * 64 + r) * R + tr * 64 + lc] = f2bf(T[lc][r]);
        }
        return;
    }
    // per-token stats: one wave per token
    {
        int w = t >> 6, lane = t & 63;
        int n = (blockIdx.x - 1 - NWCONV) * 4 + w;
        const float* x = tokens + (size_t)n * IND;
        float v[12];
        {
            float4 va = *(const float4*)(x + lane * 12);
            float4 vb = *(const float4*)(x + lane * 12 + 4);
            float4 vc = *(const float4*)(x + lane * 12 + 8);
            v[0]=va.x; v[1]=va.y; v[2]=va.z; v[3]=va.w;
            v[4]=vb.x; v[5]=vb.y; v[6]=vb.z; v[7]=vb.w;
            v[8]=vc.x; v[9]=vc.y; v[10]=vc.z; v[11]=vc.w;
        }
        float s = 0.f, s2 = 0.f, es = 0.f;
        #pragma unroll
        for (int j = 0; j < 12; ++j) { s += v[j]; s2 += v[j] * v[j]; }
        float prev = __shfl_up(v[11], 1);
        if (lane > 0) es += fabsf(v[0] - prev);
        #pragma unroll
        for (int j = 1; j < 12; ++j) es += fabsf(v[j] - v[j - 1]);
        #pragma unroll
        for (int o = 1; o < 64; o <<= 1) {
            s  += __shfl_xor(s, o);
            s2 += __shfl_xor(s2, o);
            es += __shfl_xor(es, o);
        }
        float mean = s * (1.f / 768.f);
        float var_u = (s2 - 768.f * mean * mean) * (1.f / 767.f);
        float rstd = rsqrtf(s2 * (1.f / 768.f) - mean * mean + 1e-5f);
        float edge = es * (1.f / 767.f);
        ushort xl[12];
        #pragma unroll
        for (int j = 0; j < 12; ++j) {
            int e = lane * 12 + j;
            xl[j] = f2bf((v[j] - mean) * rstd * ln_g[e] + ln_b[e]);
        }
        ushort* xd = x_ln + (size_t)n * IND + lane * 12;
        *(ushort4*)(xd)     = *(ushort4*)&xl[0];
        *(ushort4*)(xd + 4) = *(ushort4*)&xl[4];
        *(ushort4*)(xd + 8) = *(ushort4*)&xl[8];
        float hs_ = fmaxf(0.f, var_u * sw1[lane] + mean * sw1[64 + lane] + sb1[lane]);
        float he_ = fmaxf(0.f, edge * ew1[lane] + eb1[lane]);
        float acc_s = sb2[lane], acc_e = eb2[lane];
        #pragma unroll 8
        for (int j = 0; j < 64; ++j) {
            float hj = __shfl(hs_, j);
            float ej = __shfl(he_, j);
            acc_s += hj * sw2[j * 64 + lane];
            acc_e += ej * ew2[j * 64 + lane];
        }
        ushort* er = enh + (size_t)n * DHH;
        er[lane] = f2bf(acc_s);
        er[64 + lane] = f2bf(acc_e);
    }
}

// ---- GEMM1: h1 = gelu(x_ln @ pw1T^T + pb1); 128x64 tile, 8 waves (round-12 proven) ----
__global__ __launch_bounds__(512) void k_gemm1(
    const ushort* __restrict__ A, const ushort* __restrict__ BT,
    const float* __restrict__ bias, ushort* __restrict__ Cb) {
    const int N = DD2, K = IND;
    __shared__ ushort Al[128][64];
    __shared__ ushort Bl[64][64];
    int tid = threadIdx.x;
    int w = tid >> 6, lane = tid & 63;
    int g = lane >> 4, mr = lane & 15;
    int mq = w >> 1, nq = w & 1;
    int bm = blockIdx.y * 128, bn = blockIdx.x * 64;
    int r8 = lane >> 3, c = lane & 7, cg = c ^ r8;
    f32x4 acc[2][2];
    #pragma unroll
    for (int im = 0; im < 2; ++im)
        #pragma unroll
        for (int in = 0; in < 2; ++in) acc[im][in] = (f32x4){0.f, 0.f, 0.f, 0.f};
    for (int k0 = 0; k0 < K; k0 += 64) {
        #pragma unroll
        for (int i = 0; i < 2; ++i) {
            int r = 16 * w + 8 * i + r8;
            gl_lds16(A + (size_t)(bm + r) * K + k0 + cg * 8, &Al[16 * w + 8 * i][0]);
        }
        {
            int r = 8 * w + r8;
            gl_lds16(BT + (size_t)(bn + r) * K + k0 + cg * 8, &Bl[8 * w][0]);
        }
        asm volatile("s_waitcnt vmcnt(0)" ::: "memory");
        __syncthreads();
        #pragma unroll
        for (int kk = 0; kk < 64; kk += 32) {
            int jc = (kk >> 3) + g;
            int sw = ((jc ^ (mr & 7)) << 4);
            #pragma unroll
            for (int im = 0; im < 2; ++im) {
                short8 av = *(const short8*)((const char*)&Al[0][0] + (32 * mq + 16 * im + mr) * 128 + sw);
                #pragma unroll
                for (int in = 0; in < 2; ++in) {
                    short8 bv = *(const short8*)((const char*)&Bl[0][0] + (32 * nq + 16 * in + mr) * 128 + sw);
                    acc[im][in] = __builtin_amdgcn_mfma_f32_16x16x32_bf16(av, bv, acc[im][in], 0, 0, 0);
                }
            }
        }
        __syncthreads();
    }
    #pragma unroll
    for (int im = 0; im < 2; ++im) {
        #pragma unroll
        for (int in = 0; in < 2; ++in) {
            int col = bn + 32 * nq + 16 * in + mr;
            float bv = bias[col];
            #pragma unroll
            for (int r = 0; r < 4; ++r) {
                int row = bm + 32 * mq + 16 * im + 4 * g + r;
                Cb[(size_t)row * N + col] = f2bf(gelu_f(acc[im][in][r] + bv));
            }
        }
    }
}

// ---- mega-adapter, TM=32 tokens, 512 threads / 8 waves ----
// wave w: row-frag mt=w&1 (rows 16mt..16mt+15), col-group cb=64*(w>>1)
__global__ __launch_bounds__(512) void k_adapterF(
    const ushort* __restrict__ h1, const ushort* __restrict__ enh,
    const ushort* __restrict__ pw2T, const float* __restrict__ pb2,
    const float* __restrict__ emb,
    const ushort* __restrict__ fwT, const float* __restrict__ ctail,
    const float* __restrict__ fg, const float* __restrict__ fbeta,
    const ushort* __restrict__ aWT, const float* __restrict__ ab,
    const float* __restrict__ ag, const float* __restrict__ abt,
    const ushort* __restrict__ dw1T, const float* __restrict__ db1,
    const float* __restrict__ dw2, const float* __restrict__ db2,
    const int* __restrict__ sorted, const int* __restrict__ tpos,
    const int* __restrict__ tcnt, const int* __restrict__ texp,
    const int* __restrict__ meta, float* __restrict__ out) {
    // smA: phase 0-A = H1s[32][512] bf16 (32768B); phase C+ = Alf[32][264] bf16 (16896B)
    //      phase F additionally Dl[128][64] bf16 at +16896 (16384B) -> 33280B
    __shared__ __align__(16) char smA[33280];
    // smB: Bl[256][64] bf16 (32768B) during GEMMs; yf32[32][260] f32 (33280B) after
    __shared__ __align__(16) char smB[33280];
    __shared__ __align__(16) ushort EnhS[TM][128];
    __shared__ int tokS[TM];
    __shared__ float redS[4][TM][2];
    __shared__ float gateS[TM];
    __shared__ float pg[4][TM];
    ushort* H1p = (ushort*)smA;
    ushort* Alf = (ushort*)smA;              // [32][264] after phase A
    ushort* Dlp = (ushort*)(smA + 16896);    // [128][64] in phase F
    ushort* Blp = (ushort*)smB;
    float* yf32 = (float*)smB;

    int b = blockIdx.x;
    if (b >= meta[0]) return;
    int tid = threadIdx.x, w = tid >> 6, lane = tid & 63;
    int g = lane >> 4, mr = lane & 15;
    int r8 = lane >> 3, c = lane & 7, cg = c ^ r8;
    int mt = w & 1, cb = 64 * (w >> 1);
    int e = texp[b], base = tpos[b], nv = tcnt[b];
    if (tid < TM) tokS[tid] = sorted[base + min(tid, nv - 1)];
    __syncthreads();

    // stage H1s [32][512] (1 gl_lds per row) + EnhS [32][128]
    #pragma unroll
    for (int i = 0; i < 4; ++i) {
        int r = 4 * w + i;
        int tok = tokS[r];
        gl_lds16(h1 + (size_t)tok * DD2 + ((lane ^ (r & 7)) << 3), H1p + r * DD2);
    }
    {
        int row = 4 * w + (lane >> 4);
        int tok = tokS[row];
        int ch = lane & 15;
        gl_lds16(enh + (size_t)tok * DHH + ((ch ^ (row & 7)) << 3), &EnhS[4 * w][0]);
    }
    asm volatile("s_waitcnt vmcnt(0)" ::: "memory");
    __syncthreads();

    // phase A: hacc[32x256] = H1 @ pw2T^T (K=512)
    f32x4 hacc[4];
    #pragma unroll
    for (int q = 0; q < 4; ++q) hacc[q] = (f32x4){0.f, 0.f, 0.f, 0.f};
    for (int k0 = 0; k0 < DD2; k0 += 64) {
        #pragma unroll
        for (int i = 0; i < 4; ++i) {
            int r = 32 * w + 8 * i + r8;
            gl_lds16(pw2T + (size_t)r * DD2 + k0 + cg * 8, Blp + (32 * w + 8 * i) * 64);
        }
        asm volatile("s_waitcnt vmcnt(0)" ::: "memory");
        __syncthreads();
        #pragma unroll
        for (int kk = 0; kk < 64; kk += 32) {
            int jc = ((k0 + kk) >> 3) + g;
            short8 av = *(const short8*)((const char*)H1p + (16 * mt + mr) * 1024 + ((jc ^ (mr & 7)) << 4));
            int swb = (((kk >> 3) + g) ^ (mr & 7)) << 4;
            #pragma unroll
            for (int q = 0; q < 4; ++q) {
                short8 bv = *(const short8*)((const char*)Blp + (cb + 16 * q + mr) * 128 + swb);
                hacc[q] = __builtin_amdgcn_mfma_f32_16x16x32_bf16(av, bv, hacc[q], 0, 0, 0);
            }
        }
        __syncthreads();
    }
    // phase B: eacc[32x256] = EnhS @ fwT^T (K=128)
    f32x4 eacc[4];
    #pragma unroll
    for (int q = 0; q < 4; ++q) eacc[q] = (f32x4){0.f, 0.f, 0.f, 0.f};
    for (int k0 = 0; k0 < DHH; k0 += 64) {
        #pragma unroll
        for (int i = 0; i < 4; ++i) {
            int r = 32 * w + 8 * i + r8;
            gl_lds16(fwT + (size_t)r * DD + k0 + cg * 8, Blp + (32 * w + 8 * i) * 64);
        }
        asm volatile("s_waitcnt vmcnt(0)" ::: "memory");
        __syncthreads();
        #pragma unroll
        for (int kk = 0; kk < 64; kk += 32) {
            int jc = ((k0 + kk) >> 3) + g;
            short8 av = *(const short8*)((const char*)&EnhS[0][0] + (16 * mt + mr) * 256 + ((jc ^ (mr & 7)) << 4));
            int swb = (((kk >> 3) + g) ^ (mr & 7)) << 4;
            #pragma unroll
            for (int q = 0; q < 4; ++q) {
                short8 bv = *(const short8*)((const char*)Blp + (cb + 16 * q + mr) * 128 + swb);
                eacc[q] = __builtin_amdgcn_mfma_f32_16x16x32_bf16(av, bv, eacc[q], 0, 0, 0);
            }
        }
        __syncthreads();
    }
    // phase C: bias/emb/ctail add; row-LN over e_pre; hfull -> Alf (overwrites H1s)
    #pragma unroll
    for (int q = 0; q < 4; ++q) {
        int col = cb + 16 * q + mr;
        float hb = pb2[col] + emb[(size_t)e * DD + col];
        float cb2 = ctail[col];
        #pragma unroll
        for (int r4 = 0; r4 < 4; ++r4) {
            hacc[q][r4] += hb;
            eacc[q][r4] += cb2;
        }
    }
    {
        float s[4], s2[4];
        #pragma unroll
        for (int r4 = 0; r4 < 4; ++r4) {
            s[r4] = eacc[0][r4] + eacc[1][r4] + eacc[2][r4] + eacc[3][r4];
            s2[r4] = eacc[0][r4]*eacc[0][r4] + eacc[1][r4]*eacc[1][r4]
                   + eacc[2][r4]*eacc[2][r4] + eacc[3][r4]*eacc[3][r4];
        }
        #pragma unroll
        for (int o = 1; o < 16; o <<= 1) {
            #pragma unroll
            for (int r4 = 0; r4 < 4; ++r4) {
                s[r4]  += __shfl_xor(s[r4], o);
                s2[r4] += __shfl_xor(s2[r4], o);
            }
        }
        if (mr == 0) {
            #pragma unroll
            for (int r4 = 0; r4 < 4; ++r4) {
                int row = 16 * mt + 4 * g + r4;
                redS[w >> 1][row][0] = s[r4];
                redS[w >> 1][row][1] = s2[r4];
            }
        }
    }
    __syncthreads();
    #pragma unroll
    for (int r4 = 0; r4 < 4; ++r4) {
        int row = 16 * mt + 4 * g + r4;
        float S  = redS[0][row][0] + redS[1][row][0] + redS[2][row][0] + redS[3][row][0];
        float S2 = redS[0][row][1] + redS[1][row][1] + redS[2][row][1] + redS[3][row][1];
        float m = S * (1.f / 256.f);
        float rs = rsqrtf(S2 * (1.f / 256.f) - m * m + 1e-5f);
        #pragma unroll
        for (int q = 0; q < 4; ++q) {
            int col = cb + 16 * q + mr;
            float enhv = gelu_f((eacc[q][r4] - m) * rs * fg[col] + fbeta[col]);
            Alf[row * 264 + col] = f2bf(hacc[q][r4] + 0.3f * enhv);
        }
    }
    __syncthreads();
    // phase D: expert GEMM yacc[32x256] = Alf @ aWT[e]^T (K=256)
    const ushort* We = aWT + (size_t)e * DD * DD;
    f32x4 yacc[4];
    #pragma unroll
    for (int q = 0; q < 4; ++q) yacc[q] = (f32x4){0.f, 0.f, 0.f, 0.f};
    for (int k0 = 0; k0 < DD; k0 += 64) {
        #pragma unroll
        for (int i = 0; i < 4; ++i) {
            int r = 32 * w + 8 * i + r8;
            gl_lds16(We + (size_t)r * DD + k0 + cg * 8, Blp + (32 * w + 8 * i) * 64);
        }
        asm volatile("s_waitcnt vmcnt(0)" ::: "memory");
        __syncthreads();
        #pragma unroll
        for (int kk = 0; kk < 64; kk += 32) {
            short8 av = *(const short8*)&Alf[(16 * mt + mr) * 264 + k0 + kk + g * 8];
            int swb = (((kk >> 3) + g) ^ (mr & 7)) << 4;
            #pragma unroll
            for (int q = 0; q < 4; ++q) {
                short8 bv = *(const short8*)((const char*)Blp + (cb + 16 * q + mr) * 128 + swb);
                yacc[q] = __builtin_amdgcn_mfma_f32_16x16x32_bf16(av, bv, yacc[q], 0, 0, 0);
            }
        }
        __syncthreads();
    }
    // y_pre = yacc + ab -> yf32 (overwrites Bl)
    #pragma unroll
    for (int q = 0; q < 4; ++q) {
        int col = cb + 16 * q + mr;
        float abv = ab[(size_t)e * DD + col];
        #pragma unroll
        for (int r4 = 0; r4 < 4; ++r4) {
            int row = 16 * mt + 4 * g + r4;
            yf32[row * 260 + col] = yacc[q][r4] + abv;
        }
    }
    __syncthreads();
    // phase E: per-row LN(ag,abt)+gelu -> yf32 (f32) + Alf (bf16)
    #pragma unroll
    for (int i = 0; i < 4; ++i) {
        int r = 4 * w + i;
        float4 v = *(const float4*)&yf32[r * 260 + lane * 4];
        float s = v.x + v.y + v.z + v.w;
        float s2 = v.x * v.x + v.y * v.y + v.z * v.z + v.w * v.w;
        #pragma unroll
        for (int o = 1; o < 64; o <<= 1) { s += __shfl_xor(s, o); s2 += __shfl_xor(s2, o); }
        float m = s * (1.f / 256.f);
        float rs = rsqrtf(s2 * (1.f / 256.f) - m * m + 1e-5f);
        float4 gg = *(const float4*)(ag + (size_t)e * DD + lane * 4);
        float4 bb = *(const float4*)(abt + (size_t)e * DD + lane * 4);
        float4 y;
        y.x = gelu_f((v.x - m) * rs * gg.x + bb.x);
        y.y = gelu_f((v.y - m) * rs * gg.y + bb.y);
        y.z = gelu_f((v.z - m) * rs * gg.z + bb.z);
        y.w = gelu_f((v.w - m) * rs * gg.w + bb.w);
        *(float4*)&yf32[r * 260 + lane * 4] = y;
        ushort4 o4 = {f2bf(y.x), f2bf(y.y), f2bf(y.z), f2bf(y.w)};
        *(ushort4*)&Alf[r * 264 + lane * 4] = o4;
    }
    __syncthreads();
    // phase F: gate GEMM [32x128] = y_bf @ dw1T^T; wave w: col base 32*(w>>1), 2 frags
    f32x4 acc2[2];
    acc2[0] = (f32x4){0.f, 0.f, 0.f, 0.f};
    acc2[1] = (f32x4){0.f, 0.f, 0.f, 0.f};
    for (int k0 = 0; k0 < DD; k0 += 64) {
        #pragma unroll
        for (int i = 0; i < 2; ++i) {
            int r = 16 * w + 8 * i + r8;
            gl_lds16(dw1T + (size_t)r * DD + k0 + cg * 8, Dlp + (16 * w + 8 * i) * 64);
        }
        asm volatile("s_waitcnt vmcnt(0)" ::: "memory");
        __syncthreads();
        #pragma unroll
        for (int kk = 0; kk < 64; kk += 32) {
            short8 av = *(const short8*)&Alf[(16 * mt + mr) * 264 + k0 + kk + g * 8];
            int swb = (((kk >> 3) + g) ^ (mr & 7)) << 4;
            #pragma unroll
            for (int q = 0; q < 2; ++q) {
                short8 bv = *(const short8*)((const char*)Dlp + (32 * (w >> 1) + 16 * q + mr) * 128 + swb);
                acc2[q] = __builtin_amdgcn_mfma_f32_16x16x32_bf16(av, bv, acc2[q], 0, 0, 0);
            }
        }
        __syncthreads();
    }
    // phase G: gate reduce + sigmoid + scatter
    float pv[4] = {0.f, 0.f, 0.f, 0.f};
    #pragma unroll
    for (int q = 0; q < 2; ++q) {
        int col = 32 * (w >> 1) + 16 * q + mr;
        float d1 = db1[col], d2 = dw2[col];
        #pragma unroll
        for (int r4 = 0; r4 < 4; ++r4)
            pv[r4] += fmaxf(acc2[q][r4] + d1, 0.f) * d2;
    }
    #pragma unroll
    for (int o = 1; o < 16; o <<= 1) {
        #pragma unroll
        for (int r4 = 0; r4 < 4; ++r4) pv[r4] += __shfl_xor(pv[r4], o);
    }
    if (mr == 0) {
        #pragma unroll
        for (int r4 = 0; r4 < 4; ++r4)
            pg[w >> 1][16 * mt + 4 * g + r4] = pv[r4];
    }
    __syncthreads();
    if (tid < TM) {
        float p = pg[0][tid] + pg[1][tid] + pg[2][tid] + pg[3][tid] + db2[0];
        gateS[tid] = 0.8f + 0.4f / (1.f + expf(-p));
    }
    __syncthreads();
    {
        int row = tid >> 4, c0 = (tid & 15) * 16;
        if (row < nv) {
            int tok = tokS[row];
            float gt = gateS[row];
            #pragma unroll
            for (int j = 0; j < 4; ++j) {
                float4 v = *(const float4*)&yf32[row * 260 + c0 + j * 4];
                v.x *= gt; v.y *= gt; v.z *= gt; v.w *= gt;
                *(float4*)(out + (size_t)tok * DD + c0 + j * 4) = v;
            }
        }
    }
}

extern "C" void kernel_launch(void* const* d_in, const int* in_sizes, int n_in,
                              void* d_out, int out_size, void* d_ws, size_t ws_size,
                              hipStream_t stream) {
    const float* tokens = (const float*)d_in[0];
    const float* ln_g = (const float*)d_in[1];
    const float* ln_b = (const float*)d_in[2];
    const float* pw1 = (const float*)d_in[3];
    const float* pb1 = (const float*)d_in[4];
    const float* pw2 = (const float*)d_in[5];
    const float* pb2 = (const float*)d_in[6];
    const float* emb = (const float*)d_in[7];
    const float* sw1 = (const float*)d_in[8];
    const float* sb1 = (const float*)d_in[9];
    const float* sw2 = (const float*)d_in[10];
    const float* sb2 = (const float*)d_in[11];
    const float* ew1 = (const float*)d_in[12];
    const float* eb1 = (const float*)d_in[13];
    const float* ew2 = (const float*)d_in[14];
    const float* eb2 = (const float*)d_in[15];
    const float* spw1 = (const float*)d_in[16];
    const float* spb1 = (const float*)d_in[17];
    const float* spw2 = (const float*)d_in[18];
    const float* spb2 = (const float*)d_in[19];
    const float* lw1 = (const float*)d_in[20];
    const float* lb1 = (const float*)d_in[21];
    const float* lw2 = (const float*)d_in[22];
    const float* lb2 = (const float*)d_in[23];
    const float* fw = (const float*)d_in[24];
    const float* fb = (const float*)d_in[25];
    const float* fg = (const float*)d_in[26];
    const float* fbeta = (const float*)d_in[27];
    const float* aW = (const float*)d_in[28];
    const float* ab = (const float*)d_in[29];
    const float* ag = (const float*)d_in[30];
    const float* abt = (const float*)d_in[31];
    const float* dw1 = (const float*)d_in[32];
    const float* db1 = (const float*)d_in[33];
    const float* dw2 = (const float*)d_in[34];
    const float* db2 = (const float*)d_in[35];
    const int* levels = (const int*)d_in[36];
    const int* ph = (const int*)d_in[37];
    const int* pw = (const int*)d_in[38];
    float* outp = (float*)d_out;

    char* wsb = (char*)d_ws;
    ushort* x_ln  = (ushort*)wsb;  wsb += (size_t)NTOK * IND * 2;
    ushort* h1    = (ushort*)wsb;  wsb += (size_t)NTOK * DD2 * 2;
    ushort* enh   = (ushort*)wsb;  wsb += (size_t)NTOK * DHH * 2;
    ushort* pw1T  = (ushort*)wsb;  wsb += (size_t)DD2 * IND * 2;
    ushort* pw2T  = (ushort*)wsb;  wsb += (size_t)DD * DD2 * 2;
    ushort* fwT   = (ushort*)wsb;  wsb += (size_t)DD * DD * 2;
    ushort* aWT   = (ushort*)wsb;  wsb += (size_t)NEXP * DD * DD * 2;
    ushort* dw1T  = (ushort*)wsb;  wsb += (size_t)DHH * DD * 2;
    float*  ctail = (float*)wsb;   wsb += DD * 4;
    int*    sorted = (int*)wsb;    wsb += NTOK * 4;
    int*    tpos   = (int*)wsb;    wsb += NTILE_MAX * 4;
    int*    tcnt   = (int*)wsb;    wsb += NTILE_MAX * 4;
    int*    texp   = (int*)wsb;    wsb += NTILE_MAX * 4;
    int*    meta   = (int*)wsb;    wsb += 64;

    k_pre<<<1 + NWCONV + NTOK / 4, 256, 0, stream>>>(
        pw1, pw2, fw, dw1, aW, pw1T, pw2T, fwT, dw1T, aWT,
        tokens, ln_g, ln_b, sw1, sb1, sw2, sb2, ew1, eb1, ew2, eb2,
        x_ln, enh, levels,
        spw1, spb1, spw2, spb2, lw1, lb1, lw2, lb2, ph, pw, fb,
        sorted, tpos, tcnt, texp, meta, ctail);
    k_gemm1<<<dim3(DD2 / 64, NTOK / 128), 512, 0, stream>>>(x_ln, pw1T, pb1, h1);
    k_adapterF<<<NTILE_MAX, 512, 0, stream>>>(
        h1, enh, pw2T, pb2, emb, fwT, ctail, fg, fbeta,
        aWT, ab, ag, abt, dw1T, db1, dw2, db2,
        sorted, tpos, tcnt, texp, meta, outp);
}

// Round 15
// 63.468 us; speedup vs baseline: 1.0320x; 1.0320x over previous
//
#include <hip/hip_runtime.h>
#include <math.h>

#define NTOK 4096
#define IND 768
#define DD 256
#define DD2 512
#define DHH 128
#define NEXP 51
#define TM 16
#define NTILE_MAX 312
#define NWCONV 968

typedef __attribute__((ext_vector_type(4))) float f32x4;
typedef __attribute__((ext_vector_type(8))) short short8;

__device__ __forceinline__ float gelu_f(float x) {
    return 0.5f * x * (1.0f + erff(x * 0.70710678118654752440f));
}
__device__ __forceinline__ ushort f2bf(float x) {
    unsigned u = __float_as_uint(x);
    return (ushort)((u + 0x7fffu + ((u >> 16) & 1u)) >> 16);
}
// async global->LDS, 16B/lane; LDS dest = wave-uniform base + lane*16
__device__ __forceinline__ void gl_lds16(const ushort* g, ushort* l) {
    __builtin_amdgcn_global_load_lds(
        (const __attribute__((address_space(1))) unsigned int*)g,
        (__attribute__((address_space(3))) unsigned int*)l, 16, 0, 0);
}

// ---- fused pre-pass (round-13 proven; T/expS LDS union) ----
__global__ __launch_bounds__(256) void k_pre(
    const float* __restrict__ pw1, const float* __restrict__ pw2,
    const float* __restrict__ fw, const float* __restrict__ dw1,
    const float* __restrict__ aW,
    ushort* __restrict__ pw1T, ushort* __restrict__ pw2T, ushort* __restrict__ fwT,
    ushort* __restrict__ dw1T, ushort* __restrict__ aWT,
    const float* __restrict__ tokens,
    const float* __restrict__ ln_g, const float* __restrict__ ln_b,
    const float* __restrict__ sw1, const float* __restrict__ sb1,
    const float* __restrict__ sw2, const float* __restrict__ sb2,
    const float* __restrict__ ew1, const float* __restrict__ eb1,
    const float* __restrict__ ew2, const float* __restrict__ eb2,
    ushort* __restrict__ x_ln, ushort* __restrict__ enh,
    const int* __restrict__ levels,
    const float* __restrict__ spw1, const float* __restrict__ spb1,
    const float* __restrict__ spw2, const float* __restrict__ spb2,
    const float* __restrict__ lw1, const float* __restrict__ lb1,
    const float* __restrict__ lw2, const float* __restrict__ lb2,
    const int* __restrict__ ph, const int* __restrict__ pw,
    const float* __restrict__ fb,
    int* __restrict__ sorted, int* __restrict__ tpos, int* __restrict__ tcnt,
    int* __restrict__ texp, int* __restrict__ meta, float* __restrict__ ctail) {
    __shared__ __align__(16) char TU[16640];   // T[64][65] f32  OR  expS[NTOK] int
    float (*T)[65] = (float(*)[65])TU;
    int* expS = (int*)TU;
    __shared__ int cnt[NEXP], cur[NEXP], offS[NEXP + 1], tileoff[NEXP + 1];
    __shared__ float hsS[64], hlS[64], cf[128];
    int t = threadIdx.x;

    if (blockIdx.x == 0) {
        if (t < NEXP) cnt[t] = 0;
        if (t < 64) {
            float p0 = (float)ph[0], p1 = (float)pw[0];
            float lvl = (float)levels[0];
            hsS[t] = fmaxf(0.f, p0 * spw1[t] + p1 * spw1[64 + t] + spb1[t]);
            hlS[t] = fmaxf(0.f, lvl * lw1[t] + lb1[t]);
        }
        __syncthreads();
        int myidx[16];
        #pragma unroll
        for (int i = 0; i < 16; ++i) {
            int n = t + i * 256;
            int id = min(max(levels[n * 2], 0), NEXP - 1);
            myidx[i] = id;
            atomicAdd(&cnt[id], 1);
        }
        if (t < 64) {
            float v = spb2[t];
            for (int j = 0; j < 64; ++j) v += hsS[j] * spw2[j * 64 + t];
            cf[t] = v;
        } else if (t < 128) {
            int k = t - 64;
            float v = lb2[k];
            for (int j = 0; j < 64; ++j) v += hlS[j] * lw2[j * 64 + k];
            cf[64 + k] = v;
        }
        __syncthreads();
        if (t == 0) {
            int a = 0, ta = 0;
            for (int e = 0; e < NEXP; ++e) {
                offS[e] = a; cur[e] = a; tileoff[e] = ta;
                ta += (cnt[e] + TM - 1) / TM;
                a += cnt[e];
            }
            offS[NEXP] = a; tileoff[NEXP] = ta;
            meta[0] = ta;
        }
        __syncthreads();
        #pragma unroll
        for (int i = 0; i < 16; ++i) {
            int n = t + i * 256;
            int p = atomicAdd(&cur[myidx[i]], 1);
            sorted[p] = n;
            expS[p] = myidx[i];
        }
        {
            float v = fb[t];
            for (int j = 0; j < 128; ++j) v += cf[j] * fw[(size_t)(128 + j) * DD + t];
            ctail[t] = v;
        }
        __syncthreads();
        #pragma unroll
        for (int i = 0; i < 16; ++i) {
            int p = t + i * 256;
            int e = expS[p];
            int rel = p - offS[e];
            if ((rel & (TM - 1)) == 0) {
                int ti = tileoff[e] + (rel / TM);
                tpos[ti] = p;
                tcnt[ti] = min(TM, offS[e + 1] - p);
                texp[ti] = e;
            }
        }
        return;
    }
    if (blockIdx.x < 1 + NWCONV) {
        int b = blockIdx.x - 1;
        const float* src; ushort* dst; int R, C;
        if (b < 96)       { src = pw1; dst = pw1T; R = IND; C = DD2; }
        else if (b < 128) { b -= 96;  src = pw2; dst = pw2T; R = DD2; C = DD; }
        else if (b < 144) { b -= 128; src = fw;  dst = fwT;  R = DD;  C = DD; }
        else if (b < 152) { b -= 144; src = dw1; dst = dw1T; R = DD;  C = DHH; }
        else { b -= 152; int e = b >> 4; b &= 15;
               src = aW + (size_t)e * DD * DD; dst = aWT + (size_t)e * DD * DD;
               R = DD; C = DD; }
        int tpc = C >> 6;
        int tr = b / tpc, tc = b - tr * tpc;
        int lr = t >> 6, lc = t & 63;
        #pragma unroll
        for (int i = 0; i < 16; ++i) {
            int r = i * 4 + lr;
            T[r][lc] = src[(size_t)(tr * 64 + r) * C + tc * 64 + lc];
        }
        __syncthreads();
        #pragma unroll
        for (int i = 0; i < 16; ++i) {
            int r = i * 4 + lr;
            dst[(size_t)(tc * 64 + r) * R + tr * 64 + lc] = f2bf(T[lc][r]);
        }
        return;
    }
    // per-token stats: one wave per token
    {
        int w = t >> 6, lane = t & 63;
        int n = (blockIdx.x - 1 - NWCONV) * 4 + w;
        const float* x = tokens + (size_t)n * IND;
        float v[12];
        {
            float4 va = *(const float4*)(x + lane * 12);
            float4 vb = *(const float4*)(x + lane * 12 + 4);
            float4 vc = *(const float4*)(x + lane * 12 + 8);
            v[0]=va.x; v[1]=va.y; v[2]=va.z; v[3]=va.w;
            v[4]=vb.x; v[5]=vb.y; v[6]=vb.z; v[7]=vb.w;
            v[8]=vc.x; v[9]=vc.y; v[10]=vc.z; v[11]=vc.w;
        }
        float s = 0.f, s2 = 0.f, es = 0.f;
        #pragma unroll
        for (int j = 0; j < 12; ++j) { s += v[j]; s2 += v[j] * v[j]; }
        float prev = __shfl_up(v[11], 1);
        if (lane > 0) es += fabsf(v[0] - prev);
        #pragma unroll
        for (int j = 1; j < 12; ++j) es += fabsf(v[j] - v[j - 1]);
        #pragma unroll
        for (int o = 1; o < 64; o <<= 1) {
            s  += __shfl_xor(s, o);
            s2 += __shfl_xor(s2, o);
            es += __shfl_xor(es, o);
        }
        float mean = s * (1.f / 768.f);
        float var_u = (s2 - 768.f * mean * mean) * (1.f / 767.f);
        float rstd = rsqrtf(s2 * (1.f / 768.f) - mean * mean + 1e-5f);
        float edge = es * (1.f / 767.f);
        ushort xl[12];
        #pragma unroll
        for (int j = 0; j < 12; ++j) {
            int e = lane * 12 + j;
            xl[j] = f2bf((v[j] - mean) * rstd * ln_g[e] + ln_b[e]);
        }
        ushort* xd = x_ln + (size_t)n * IND + lane * 12;
        *(ushort4*)(xd)     = *(ushort4*)&xl[0];
        *(ushort4*)(xd + 4) = *(ushort4*)&xl[4];
        *(ushort4*)(xd + 8) = *(ushort4*)&xl[8];
        float hs_ = fmaxf(0.f, var_u * sw1[lane] + mean * sw1[64 + lane] + sb1[lane]);
        float he_ = fmaxf(0.f, edge * ew1[lane] + eb1[lane]);
        float acc_s = sb2[lane], acc_e = eb2[lane];
        #pragma unroll 8
        for (int j = 0; j < 64; ++j) {
            float hj = __shfl(hs_, j);
            float ej = __shfl(he_, j);
            acc_s += hj * sw2[j * 64 + lane];
            acc_e += ej * ew2[j * 64 + lane];
        }
        ushort* er = enh + (size_t)n * DHH;
        er[lane] = f2bf(acc_s);
        er[64 + lane] = f2bf(acc_e);
    }
}

// ---- GEMM1: h1 = gelu(x_ln @ pw1T^T + pb1); 128x64 tile, 8 waves (round-12 proven) ----
__global__ __launch_bounds__(512) void k_gemm1(
    const ushort* __restrict__ A, const ushort* __restrict__ BT,
    const float* __restrict__ bias, ushort* __restrict__ Cb) {
    const int N = DD2, K = IND;
    __shared__ ushort Al[128][64];
    __shared__ ushort Bl[64][64];
    int tid = threadIdx.x;
    int w = tid >> 6, lane = tid & 63;
    int g = lane >> 4, mr = lane & 15;
    int mq = w >> 1, nq = w & 1;
    int bm = blockIdx.y * 128, bn = blockIdx.x * 64;
    int r8 = lane >> 3, c = lane & 7, cg = c ^ r8;
    f32x4 acc[2][2];
    #pragma unroll
    for (int im = 0; im < 2; ++im)
        #pragma unroll
        for (int in = 0; in < 2; ++in) acc[im][in] = (f32x4){0.f, 0.f, 0.f, 0.f};
    for (int k0 = 0; k0 < K; k0 += 64) {
        #pragma unroll
        for (int i = 0; i < 2; ++i) {
            int r = 16 * w + 8 * i + r8;
            gl_lds16(A + (size_t)(bm + r) * K + k0 + cg * 8, &Al[16 * w + 8 * i][0]);
        }
        {
            int r = 8 * w + r8;
            gl_lds16(BT + (size_t)(bn + r) * K + k0 + cg * 8, &Bl[8 * w][0]);
        }
        asm volatile("s_waitcnt vmcnt(0)" ::: "memory");
        __syncthreads();
        #pragma unroll
        for (int kk = 0; kk < 64; kk += 32) {
            int jc = (kk >> 3) + g;
            int sw = ((jc ^ (mr & 7)) << 4);
            #pragma unroll
            for (int im = 0; im < 2; ++im) {
                short8 av = *(const short8*)((const char*)&Al[0][0] + (32 * mq + 16 * im + mr) * 128 + sw);
                #pragma unroll
                for (int in = 0; in < 2; ++in) {
                    short8 bv = *(const short8*)((const char*)&Bl[0][0] + (32 * nq + 16 * in + mr) * 128 + sw);
                    acc[im][in] = __builtin_amdgcn_mfma_f32_16x16x32_bf16(av, bv, acc[im][in], 0, 0, 0);
                }
            }
        }
        __syncthreads();
    }
    #pragma unroll
    for (int im = 0; im < 2; ++im) {
        #pragma unroll
        for (int in = 0; in < 2; ++in) {
            int col = bn + 32 * nq + 16 * in + mr;
            float bv = bias[col];
            #pragma unroll
            for (int r = 0; r < 4; ++r) {
                int row = bm + 32 * mq + 16 * im + 4 * g + r;
                Cb[(size_t)row * N + col] = f2bf(gelu_f(acc[im][in][r] + bv));
            }
        }
    }
}

// ---- mega-adapter, TM=16 tokens, 512 threads / 8 waves ----
// wave w owns rows 0..15 (single row-frag), col-group cb=32*w (2 frags) for A/B/D
__global__ __launch_bounds__(512) void k_adapterF(
    const ushort* __restrict__ h1, const ushort* __restrict__ enh,
    const ushort* __restrict__ pw2T, const float* __restrict__ pb2,
    const float* __restrict__ emb,
    const ushort* __restrict__ fwT, const float* __restrict__ ctail,
    const float* __restrict__ fg, const float* __restrict__ fbeta,
    const ushort* __restrict__ aWT, const float* __restrict__ ab,
    const float* __restrict__ ag, const float* __restrict__ abt,
    const ushort* __restrict__ dw1T, const float* __restrict__ db1,
    const float* __restrict__ dw2, const float* __restrict__ db2,
    const int* __restrict__ sorted, const int* __restrict__ tpos,
    const int* __restrict__ tcnt, const int* __restrict__ texp,
    const int* __restrict__ meta, float* __restrict__ out) {
    // smA: phases 0-A = H1s[16][512] bf16 (16384B);
    //      phase C+: Alf[16][264] bf16 (8448B), phase F adds Dl[128][64] at +8448 (16384B)
    __shared__ __align__(16) char smA[24832];
    // smB: Bl[256][64] bf16 (32768B) during GEMMs; yf32[16][260] f32 (16640B) after
    __shared__ __align__(16) char smB[32768];
    __shared__ __align__(16) ushort EnhS[TM][128];
    __shared__ int tokS[TM];
    __shared__ float redS[8][TM][2];
    __shared__ float gateS[TM];
    __shared__ float pg[8][TM];
    ushort* H1p = (ushort*)smA;
    ushort* Alf = (ushort*)smA;
    ushort* Dlp = (ushort*)(smA + 8448);
    ushort* Blp = (ushort*)smB;
    float* yf32 = (float*)smB;

    int b = blockIdx.x;
    if (b >= meta[0]) return;
    int tid = threadIdx.x, w = tid >> 6, lane = tid & 63;
    int g = lane >> 4, mr = lane & 15;
    int r8 = lane >> 3, c = lane & 7, cg = c ^ r8;
    int cb = 32 * w;
    int e = texp[b], base = tpos[b], nv = tcnt[b];
    if (tid < TM) tokS[tid] = sorted[base + min(tid, nv - 1)];
    __syncthreads();

    // stage H1s [16][512]: 2 rows per wave ; EnhS [16][128]: waves 0-3, 4 rows each
    #pragma unroll
    for (int i = 0; i < 2; ++i) {
        int r = 2 * w + i;
        int tok = tokS[r];
        gl_lds16(h1 + (size_t)tok * DD2 + ((lane ^ (r & 7)) << 3), H1p + r * DD2);
    }
    if (w < 4) {
        int row = 4 * w + (lane >> 4);
        int tok = tokS[row];
        int ch = lane & 15;
        gl_lds16(enh + (size_t)tok * DHH + ((ch ^ (row & 7)) << 3), &EnhS[4 * w][0]);
    }
    asm volatile("s_waitcnt vmcnt(0)" ::: "memory");
    __syncthreads();

    // phase A: hacc[16 x (cb..cb+31)] = H1 @ pw2T^T (K=512)
    f32x4 hacc[2];
    hacc[0] = (f32x4){0.f, 0.f, 0.f, 0.f};
    hacc[1] = (f32x4){0.f, 0.f, 0.f, 0.f};
    for (int k0 = 0; k0 < DD2; k0 += 64) {
        #pragma unroll
        for (int i = 0; i < 4; ++i) {
            int r = 32 * w + 8 * i + r8;
            gl_lds16(pw2T + (size_t)r * DD2 + k0 + cg * 8, Blp + (32 * w + 8 * i) * 64);
        }
        asm volatile("s_waitcnt vmcnt(0)" ::: "memory");
        __syncthreads();
        #pragma unroll
        for (int kk = 0; kk < 64; kk += 32) {
            int jc = ((k0 + kk) >> 3) + g;
            short8 av = *(const short8*)((const char*)H1p + mr * 1024 + ((jc ^ (mr & 7)) << 4));
            int swb = (((kk >> 3) + g) ^ (mr & 7)) << 4;
            #pragma unroll
            for (int q = 0; q < 2; ++q) {
                short8 bv = *(const short8*)((const char*)Blp + (cb + 16 * q + mr) * 128 + swb);
                hacc[q] = __builtin_amdgcn_mfma_f32_16x16x32_bf16(av, bv, hacc[q], 0, 0, 0);
            }
        }
        __syncthreads();
    }
    // phase B: eacc[16 x 32] = EnhS @ fwT^T (K=128)
    f32x4 eacc[2];
    eacc[0] = (f32x4){0.f, 0.f, 0.f, 0.f};
    eacc[1] = (f32x4){0.f, 0.f, 0.f, 0.f};
    for (int k0 = 0; k0 < DHH; k0 += 64) {
        #pragma unroll
        for (int i = 0; i < 4; ++i) {
            int r = 32 * w + 8 * i + r8;
            gl_lds16(fwT + (size_t)r * DD + k0 + cg * 8, Blp + (32 * w + 8 * i) * 64);
        }
        asm volatile("s_waitcnt vmcnt(0)" ::: "memory");
        __syncthreads();
        #pragma unroll
        for (int kk = 0; kk < 64; kk += 32) {
            int jc = ((k0 + kk) >> 3) + g;
            short8 av = *(const short8*)((const char*)&EnhS[0][0] + mr * 256 + ((jc ^ (mr & 7)) << 4));
            int swb = (((kk >> 3) + g) ^ (mr & 7)) << 4;
            #pragma unroll
            for (int q = 0; q < 2; ++q) {
                short8 bv = *(const short8*)((const char*)Blp + (cb + 16 * q + mr) * 128 + swb);
                eacc[q] = __builtin_amdgcn_mfma_f32_16x16x32_bf16(av, bv, eacc[q], 0, 0, 0);
            }
        }
        __syncthreads();
    }
    // phase C: bias/emb/ctail; LN over e_pre rows (reduce across 8 waves); hfull -> Alf
    #pragma unroll
    for (int q = 0; q < 2; ++q) {
        int col = cb + 16 * q + mr;
        float hb = pb2[col] + emb[(size_t)e * DD + col];
        float cb2 = ctail[col];
        #pragma unroll
        for (int r4 = 0; r4 < 4; ++r4) {
            hacc[q][r4] += hb;
            eacc[q][r4] += cb2;
        }
    }
    {
        float s[4], s2[4];
        #pragma unroll
        for (int r4 = 0; r4 < 4; ++r4) {
            s[r4] = eacc[0][r4] + eacc[1][r4];
            s2[r4] = eacc[0][r4] * eacc[0][r4] + eacc[1][r4] * eacc[1][r4];
        }
        #pragma unroll
        for (int o = 1; o < 16; o <<= 1) {
            #pragma unroll
            for (int r4 = 0; r4 < 4; ++r4) {
                s[r4]  += __shfl_xor(s[r4], o);
                s2[r4] += __shfl_xor(s2[r4], o);
            }
        }
        if (mr == 0) {
            #pragma unroll
            for (int r4 = 0; r4 < 4; ++r4) {
                redS[w][4 * g + r4][0] = s[r4];
                redS[w][4 * g + r4][1] = s2[r4];
            }
        }
    }
    __syncthreads();
    #pragma unroll
    for (int r4 = 0; r4 < 4; ++r4) {
        int row = 4 * g + r4;
        float S = 0.f, S2 = 0.f;
        #pragma unroll
        for (int ww = 0; ww < 8; ++ww) { S += redS[ww][row][0]; S2 += redS[ww][row][1]; }
        float m = S * (1.f / 256.f);
        float rs = rsqrtf(S2 * (1.f / 256.f) - m * m + 1e-5f);
        #pragma unroll
        for (int q = 0; q < 2; ++q) {
            int col = cb + 16 * q + mr;
            float enhv = gelu_f((eacc[q][r4] - m) * rs * fg[col] + fbeta[col]);
            Alf[row * 264 + col] = f2bf(hacc[q][r4] + 0.3f * enhv);
        }
    }
    __syncthreads();
    // phase D: expert GEMM yacc[16 x 32] = Alf @ aWT[e]^T (K=256)
    const ushort* We = aWT + (size_t)e * DD * DD;
    f32x4 yacc[2];
    yacc[0] = (f32x4){0.f, 0.f, 0.f, 0.f};
    yacc[1] = (f32x4){0.f, 0.f, 0.f, 0.f};
    for (int k0 = 0; k0 < DD; k0 += 64) {
        #pragma unroll
        for (int i = 0; i < 4; ++i) {
            int r = 32 * w + 8 * i + r8;
            gl_lds16(We + (size_t)r * DD + k0 + cg * 8, Blp + (32 * w + 8 * i) * 64);
        }
        asm volatile("s_waitcnt vmcnt(0)" ::: "memory");
        __syncthreads();
        #pragma unroll
        for (int kk = 0; kk < 64; kk += 32) {
            short8 av = *(const short8*)&Alf[mr * 264 + k0 + kk + g * 8];
            int swb = (((kk >> 3) + g) ^ (mr & 7)) << 4;
            #pragma unroll
            for (int q = 0; q < 2; ++q) {
                short8 bv = *(const short8*)((const char*)Blp + (cb + 16 * q + mr) * 128 + swb);
                yacc[q] = __builtin_amdgcn_mfma_f32_16x16x32_bf16(av, bv, yacc[q], 0, 0, 0);
            }
        }
        __syncthreads();
    }
    // y_pre = yacc + ab -> yf32 (overwrites Bl)
    #pragma unroll
    for (int q = 0; q < 2; ++q) {
        int col = cb + 16 * q + mr;
        float abv = ab[(size_t)e * DD + col];
        #pragma unroll
        for (int r4 = 0; r4 < 4; ++r4) {
            yf32[(4 * g + r4) * 260 + col] = yacc[q][r4] + abv;
        }
    }
    __syncthreads();
    // phase E: per-row LN(ag,abt)+gelu -> yf32 (f32) + Alf (bf16); 2 rows per wave
    #pragma unroll
    for (int i = 0; i < 2; ++i) {
        int r = 2 * w + i;
        float4 v = *(const float4*)&yf32[r * 260 + lane * 4];
        float s = v.x + v.y + v.z + v.w;
        float s2 = v.x * v.x + v.y * v.y + v.z * v.z + v.w * v.w;
        #pragma unroll
        for (int o = 1; o < 64; o <<= 1) { s += __shfl_xor(s, o); s2 += __shfl_xor(s2, o); }
        float m = s * (1.f / 256.f);
        float rs = rsqrtf(s2 * (1.f / 256.f) - m * m + 1e-5f);
        float4 gg = *(const float4*)(ag + (size_t)e * DD + lane * 4);
        float4 bb = *(const float4*)(abt + (size_t)e * DD + lane * 4);
        float4 y;
        y.x = gelu_f((v.x - m) * rs * gg.x + bb.x);
        y.y = gelu_f((v.y - m) * rs * gg.y + bb.y);
        y.z = gelu_f((v.z - m) * rs * gg.z + bb.z);
        y.w = gelu_f((v.w - m) * rs * gg.w + bb.w);
        *(float4*)&yf32[r * 260 + lane * 4] = y;
        ushort4 o4 = {f2bf(y.x), f2bf(y.y), f2bf(y.z), f2bf(y.w)};
        *(ushort4*)&Alf[r * 264 + lane * 4] = o4;
    }
    __syncthreads();
    // phase F: gate GEMM [16 x 128] = y_bf @ dw1T^T; wave w -> cols 16w..16w+15 (1 frag)
    f32x4 acc2 = (f32x4){0.f, 0.f, 0.f, 0.f};
    for (int k0 = 0; k0 < DD; k0 += 64) {
        #pragma unroll
        for (int i = 0; i < 2; ++i) {
            int r = 16 * w + 8 * i + r8;
            gl_lds16(dw1T + (size_t)r * DD + k0 + cg * 8, Dlp + (16 * w + 8 * i) * 64);
        }
        asm volatile("s_waitcnt vmcnt(0)" ::: "memory");
        __syncthreads();
        #pragma unroll
        for (int kk = 0; kk < 64; kk += 32) {
            short8 av = *(const short8*)&Alf[mr * 264 + k0 + kk + g * 8];
            int swb = (((kk >> 3) + g) ^ (mr & 7)) << 4;
            short8 bv = *(const short8*)((const char*)Dlp + (16 * w + mr) * 128 + swb);
            acc2 = __builtin_amdgcn_mfma_f32_16x16x32_bf16(av, bv, acc2, 0, 0, 0);
        }
        __syncthreads();
    }
    // phase G: gate reduce + sigmoid + scatter
    {
        int col = 16 * w + mr;
        float d1 = db1[col], d2 = dw2[col];
        float pv[4];
        #pragma unroll
        for (int r4 = 0; r4 < 4; ++r4)
            pv[r4] = fmaxf(acc2[r4] + d1, 0.f) * d2;
        #pragma unroll
        for (int o = 1; o < 16; o <<= 1) {
            #pragma unroll
            for (int r4 = 0; r4 < 4; ++r4) pv[r4] += __shfl_xor(pv[r4], o);
        }
        if (mr == 0) {
            #pragma unroll
            for (int r4 = 0; r4 < 4; ++r4)
                pg[w][4 * g + r4] = pv[r4];
        }
    }
    __syncthreads();
    if (tid < TM) {
        float p = db2[0];
        #pragma unroll
        for (int ww = 0; ww < 8; ++ww) p += pg[ww][tid];
        gateS[tid] = 0.8f + 0.4f / (1.f + expf(-p));
    }
    __syncthreads();
    {
        int row = tid >> 5, c0 = (tid & 31) * 8;
        if (row < nv) {
            int tok = tokS[row];
            float gt = gateS[row];
            #pragma unroll
            for (int j = 0; j < 2; ++j) {
                float4 v = *(const float4*)&yf32[row * 260 + c0 + j * 4];
                v.x *= gt; v.y *= gt; v.z *= gt; v.w *= gt;
                *(float4*)(out + (size_t)tok * DD + c0 + j * 4) = v;
            }
        }
    }
}

extern "C" void kernel_launch(void* const* d_in, const int* in_sizes, int n_in,
                              void* d_out, int out_size, void* d_ws, size_t ws_size,
                              hipStream_t stream) {
    const float* tokens = (const float*)d_in[0];
    const float* ln_g = (const float*)d_in[1];
    const float* ln_b = (const float*)d_in[2];
    const float* pw1 = (const float*)d_in[3];
    const float* pb1 = (const float*)d_in[4];
    const float* pw2 = (const float*)d_in[5];
    const float* pb2 = (const float*)d_in[6];
    const float* emb = (const float*)d_in[7];
    const float* sw1 = (const float*)d_in[8];
    const float* sb1 = (const float*)d_in[9];
    const float* sw2 = (const float*)d_in[10];
    const float* sb2 = (const float*)d_in[11];
    const float* ew1 = (const float*)d_in[12];
    const float* eb1 = (const float*)d_in[13];
    const float* ew2 = (const float*)d_in[14];
    const float* eb2 = (const float*)d_in[15];
    const float* spw1 = (const float*)d_in[16];
    const float* spb1 = (const float*)d_in[17];
    const float* spw2 = (const float*)d_in[18];
    const float* spb2 = (const float*)d_in[19];
    const float* lw1 = (const float*)d_in[20];
    const float* lb1 = (const float*)d_in[21];
    const float* lw2 = (const float*)d_in[22];
    const float* lb2 = (const float*)d_in[23];
    const float* fw = (const float*)d_in[24];
    const float* fb = (const float*)d_in[25];
    const float* fg = (const float*)d_in[26];
    const float* fbeta = (const float*)d_in[27];
    const float* aW = (const float*)d_in[28];
    const float* ab = (const float*)d_in[29];
    const float* ag = (const float*)d_in[30];
    const float* abt = (const float*)d_in[31];
    const float* dw1 = (const float*)d_in[32];
    const float* db1 = (const float*)d_in[33];
    const float* dw2 = (const float*)d_in[34];
    const float* db2 = (const float*)d_in[35];
    const int* levels = (const int*)d_in[36];
    const int* ph = (const int*)d_in[37];
    const int* pw = (const int*)d_in[38];
    float* outp = (float*)d_out;

    char* wsb = (char*)d_ws;
    ushort* x_ln  = (ushort*)wsb;  wsb += (size_t)NTOK * IND * 2;
    ushort* h1    = (ushort*)wsb;  wsb += (size_t)NTOK * DD2 * 2;
    ushort* enh   = (ushort*)wsb;  wsb += (size_t)NTOK * DHH * 2;
    ushort* pw1T  = (ushort*)wsb;  wsb += (size_t)DD2 * IND * 2;
    ushort* pw2T  = (ushort*)wsb;  wsb += (size_t)DD * DD2 * 2;
    ushort* fwT   = (ushort*)wsb;  wsb += (size_t)DD * DD * 2;
    ushort* aWT   = (ushort*)wsb;  wsb += (size_t)NEXP * DD * DD * 2;
    ushort* dw1T  = (ushort*)wsb;  wsb += (size_t)DHH * DD * 2;
    float*  ctail = (float*)wsb;   wsb += DD * 4;
    int*    sorted = (int*)wsb;    wsb += NTOK * 4;
    int*    tpos   = (int*)wsb;    wsb += NTILE_MAX * 4;
    int*    tcnt   = (int*)wsb;    wsb += NTILE_MAX * 4;
    int*    texp   = (int*)wsb;    wsb += NTILE_MAX * 4;
    int*    meta   = (int*)wsb;    wsb += 64;

    k_pre<<<1 + NWCONV + NTOK / 4, 256, 0, stream>>>(
        pw1, pw2, fw, dw1, aW, pw1T, pw2T, fwT, dw1T, aWT,
        tokens, ln_g, ln_b, sw1, sb1, sw2, sb2, ew1, eb1, ew2, eb2,
        x_ln, enh, levels,
        spw1, spb1, spw2, spb2, lw1, lb1, lw2, lb2, ph, pw, fb,
        sorted, tpos, tcnt, texp, meta, ctail);
    k_gemm1<<<dim3(DD2 / 64, NTOK / 128), 512, 0, stream>>>(x_ln, pw1T, pb1, h1);
    k_adapterF<<<NTILE_MAX, 512, 0, stream>>>(
        h1, enh, pw2T, pb2, emb, fwT, ctail, fg, fbeta,
        aWT, ab, ag, abt, dw1T, db1, dw2, db2,
        sorted, tpos, tcnt, texp, meta, outp);
}